// Round 2
// baseline (567.615 us; speedup 1.0000x reference)
//
#include <hip/hip_runtime.h>

// Problem constants (from reference)
#define N_NODES 100000
#define N_EDGES 1600000
#define D_FEAT  32
#define CAP     64   // per-node edge-list capacity; deg ~ Poisson(16), max ~45

// ---------------- bucketed path ----------------

// One thread per edge: claim a slot in dst's bucket, record edge id.
__global__ void sage_scatter_kernel(const int* __restrict__ dst,
                                    int* __restrict__ cnt,    // [N], pre-zeroed
                                    int* __restrict__ list) { // [N*CAP]
    int e = blockIdx.x * blockDim.x + threadIdx.x;
    if (e >= N_EDGES) return;
    int d = dst[e];
    int slot = atomicAdd(&cnt[d], 1);
    if (slot < CAP) list[d * CAP + slot] = e;
}

// Half-wave (32 lanes = 32 feats) per node: walk edge list, accumulate in
// registers, fused mean + residual store. No float atomics anywhere.
__global__ void sage_gather_kernel(const float* __restrict__ rel,
                                   const float* __restrict__ pattern,
                                   const int*   __restrict__ src,
                                   const int*   __restrict__ cnt,
                                   const int*   __restrict__ list,
                                   float* __restrict__ out) {
    int t = blockIdx.x * blockDim.x + threadIdx.x;  // t = n*32 + f
    int n = t >> 5;
    int f = t & 31;
    if (n >= N_NODES) return;

    int deg = cnt[n];
    int m = min(deg, CAP);
    const int* lp = list + n * CAP;

    float sum = 0.0f;
    // 1-deep software pipeline: prefetch next (edge id, src) while the
    // current iteration's rel/pattern loads are in flight.
    int e_cur = 0, s_cur = 0;
    if (m > 0) { e_cur = lp[0]; s_cur = src[e_cur]; }
    for (int j = 0; j < m; ++j) {
        int e_nxt = 0, s_nxt = 0;
        if (j + 1 < m) { e_nxt = lp[j + 1]; s_nxt = src[e_nxt]; }
        sum += rel[s_cur * D_FEAT + f] * pattern[e_cur * D_FEAT + f];
        e_cur = e_nxt; s_cur = s_nxt;
    }

    out[t] = sum / fmaxf((float)deg, 1.0f) + rel[t];
}

// ---------------- fallback (round-1 atomic path), used only if ws too small ----------------

__global__ void sage_edge_atomic_kernel(const float* __restrict__ rel,
                                        const float* __restrict__ pattern,
                                        const int*   __restrict__ src,
                                        const int*   __restrict__ dst,
                                        float* __restrict__ sums,
                                        float* __restrict__ deg) {
    int i = blockIdx.x * blockDim.x + threadIdx.x;
    if (i >= N_EDGES * D_FEAT) return;
    int e = i >> 5;
    int f = i & 31;
    float m = rel[src[e] * D_FEAT + f] * pattern[i];
    atomicAdd(&sums[dst[e] * D_FEAT + f], m);
    if (f == 0) atomicAdd(&deg[dst[e]], 1.0f);
}

__global__ void sage_node_atomic_kernel(const float* __restrict__ rel,
                                        const float* __restrict__ deg,
                                        float* __restrict__ out) {
    int i = blockIdx.x * blockDim.x + threadIdx.x;
    if (i >= N_NODES * D_FEAT) return;
    out[i] = out[i] / fmaxf(deg[i >> 5], 1.0f) + rel[i];
}

extern "C" void kernel_launch(void* const* d_in, const int* in_sizes, int n_in,
                              void* d_out, int out_size, void* d_ws, size_t ws_size,
                              hipStream_t stream) {
    const float* rel     = (const float*)d_in[0];
    const float* pattern = (const float*)d_in[1];
    const int*   src     = (const int*)d_in[2];
    const int*   dst     = (const int*)d_in[3];
    float* out = (float*)d_out;

    size_t need = (size_t)N_NODES * (CAP + 1) * sizeof(int);  // cnt + list ≈ 26 MB

    if (ws_size >= need) {
        int* cnt  = (int*)d_ws;            // [N]
        int* list = cnt + N_NODES;         // [N*CAP]

        hipMemsetAsync(cnt, 0, sizeof(int) * N_NODES, stream);

        sage_scatter_kernel<<<(N_EDGES + 255) / 256, 256, 0, stream>>>(dst, cnt, list);

        int node_threads = N_NODES * D_FEAT;
        sage_gather_kernel<<<(node_threads + 255) / 256, 256, 0, stream>>>(
            rel, pattern, src, cnt, list, out);
    } else {
        // ws too small for buckets: atomic fallback (round-1 algorithm)
        float* deg = (float*)d_ws;  // [N] floats = 400 KB
        hipMemsetAsync(out, 0, sizeof(float) * N_NODES * D_FEAT, stream);
        hipMemsetAsync(deg, 0, sizeof(float) * N_NODES, stream);
        sage_edge_atomic_kernel<<<(N_EDGES * D_FEAT + 255) / 256, 256, 0, stream>>>(
            rel, pattern, src, dst, out, deg);
        sage_node_atomic_kernel<<<(N_NODES * D_FEAT + 255) / 256, 256, 0, stream>>>(
            rel, deg, out);
    }
}

// Round 3
// 465.073 us; speedup vs baseline: 1.2205x; 1.2205x over previous
//
#include <hip/hip_runtime.h>

// Problem constants (from reference)
#define N_NODES 100000
#define N_EDGES 1600000
#define D_FEAT  32
#define CAP     64   // per-node edge-list capacity; deg ~ Poisson(16), max ~40 over 100K draws

// ---------------- bucketed path ----------------

// One thread per edge: claim a slot in dst's bucket, record edge id.
__global__ void sage_scatter_kernel(const int* __restrict__ dst,
                                    int* __restrict__ cnt,    // [N], pre-zeroed
                                    int* __restrict__ list) { // [N*CAP]
    int e = blockIdx.x * blockDim.x + threadIdx.x;
    if (e >= N_EDGES) return;
    int d = dst[e];
    int slot = atomicAdd(&cnt[d], 1);
    if (slot < CAP) list[d * CAP + slot] = e;
}

// Half-wave (32 lanes = 32 feats) per node. Edge ids batched via int4 and
// unrolled 8-wide so each step issues 2 list loads + 8 src loads + 16
// rel/pattern line loads, all independent -> ~8x memory-level parallelism
// over the naive dependent walk. No float atomics anywhere.
__global__ void sage_gather_kernel(const float* __restrict__ rel,
                                   const float* __restrict__ pattern,
                                   const int*   __restrict__ src,
                                   const int*   __restrict__ cnt,
                                   const int*   __restrict__ list,
                                   float* __restrict__ out) {
    int t = blockIdx.x * blockDim.x + threadIdx.x;  // t = n*32 + f
    int n = t >> 5;
    int f = t & 31;
    if (n >= N_NODES) return;

    int deg = cnt[n];
    int m = min(deg, CAP);
    const int* lp = list + n * CAP;   // 16B-aligned: list base offset 400000B, bucket stride 256B

    float sum = 0.0f;
    int j = 0;

    // 8-wide unrolled body: all loads within a group are independent.
    for (; j + 8 <= m; j += 8) {
        int4 a = *(const int4*)(lp + j);
        int4 b = *(const int4*)(lp + j + 4);
        int s0 = src[a.x], s1 = src[a.y], s2 = src[a.z], s3 = src[a.w];
        int s4 = src[b.x], s5 = src[b.y], s6 = src[b.z], s7 = src[b.w];
        float r0 = rel[s0 * D_FEAT + f], p0 = pattern[a.x * D_FEAT + f];
        float r1 = rel[s1 * D_FEAT + f], p1 = pattern[a.y * D_FEAT + f];
        float r2 = rel[s2 * D_FEAT + f], p2 = pattern[a.z * D_FEAT + f];
        float r3 = rel[s3 * D_FEAT + f], p3 = pattern[a.w * D_FEAT + f];
        float r4 = rel[s4 * D_FEAT + f], p4 = pattern[b.x * D_FEAT + f];
        float r5 = rel[s5 * D_FEAT + f], p5 = pattern[b.y * D_FEAT + f];
        float r6 = rel[s6 * D_FEAT + f], p6 = pattern[b.z * D_FEAT + f];
        float r7 = rel[s7 * D_FEAT + f], p7 = pattern[b.w * D_FEAT + f];
        sum += r0 * p0; sum += r1 * p1; sum += r2 * p2; sum += r3 * p3;
        sum += r4 * p4; sum += r5 * p5; sum += r6 * p6; sum += r7 * p7;
    }
    // 4-wide step
    for (; j + 4 <= m; j += 4) {
        int4 a = *(const int4*)(lp + j);
        int s0 = src[a.x], s1 = src[a.y], s2 = src[a.z], s3 = src[a.w];
        float r0 = rel[s0 * D_FEAT + f], p0 = pattern[a.x * D_FEAT + f];
        float r1 = rel[s1 * D_FEAT + f], p1 = pattern[a.y * D_FEAT + f];
        float r2 = rel[s2 * D_FEAT + f], p2 = pattern[a.z * D_FEAT + f];
        float r3 = rel[s3 * D_FEAT + f], p3 = pattern[a.w * D_FEAT + f];
        sum += r0 * p0; sum += r1 * p1; sum += r2 * p2; sum += r3 * p3;
    }
    // scalar tail (<=3)
    for (; j < m; ++j) {
        int e = lp[j];
        sum += rel[src[e] * D_FEAT + f] * pattern[e * D_FEAT + f];
    }

    out[t] = sum / fmaxf((float)deg, 1.0f) + rel[t];
}

// ---------------- fallback (atomic path), used only if ws too small ----------------

__global__ void sage_edge_atomic_kernel(const float* __restrict__ rel,
                                        const float* __restrict__ pattern,
                                        const int*   __restrict__ src,
                                        const int*   __restrict__ dst,
                                        float* __restrict__ sums,
                                        float* __restrict__ deg) {
    int i = blockIdx.x * blockDim.x + threadIdx.x;
    if (i >= N_EDGES * D_FEAT) return;
    int e = i >> 5;
    int f = i & 31;
    float m = rel[src[e] * D_FEAT + f] * pattern[i];
    atomicAdd(&sums[dst[e] * D_FEAT + f], m);
    if (f == 0) atomicAdd(&deg[dst[e]], 1.0f);
}

__global__ void sage_node_atomic_kernel(const float* __restrict__ rel,
                                        const float* __restrict__ deg,
                                        float* __restrict__ out) {
    int i = blockIdx.x * blockDim.x + threadIdx.x;
    if (i >= N_NODES * D_FEAT) return;
    out[i] = out[i] / fmaxf(deg[i >> 5], 1.0f) + rel[i];
}

extern "C" void kernel_launch(void* const* d_in, const int* in_sizes, int n_in,
                              void* d_out, int out_size, void* d_ws, size_t ws_size,
                              hipStream_t stream) {
    const float* rel     = (const float*)d_in[0];
    const float* pattern = (const float*)d_in[1];
    const int*   src     = (const int*)d_in[2];
    const int*   dst     = (const int*)d_in[3];
    float* out = (float*)d_out;

    size_t need = (size_t)N_NODES * (CAP + 1) * sizeof(int);  // cnt + list ≈ 26 MB

    if (ws_size >= need) {
        int* cnt  = (int*)d_ws;            // [N]
        int* list = cnt + N_NODES;         // [N*CAP]

        hipMemsetAsync(cnt, 0, sizeof(int) * N_NODES, stream);

        sage_scatter_kernel<<<(N_EDGES + 255) / 256, 256, 0, stream>>>(dst, cnt, list);

        int node_threads = N_NODES * D_FEAT;
        sage_gather_kernel<<<(node_threads + 255) / 256, 256, 0, stream>>>(
            rel, pattern, src, cnt, list, out);
    } else {
        // ws too small for buckets: atomic fallback
        float* deg = (float*)d_ws;  // [N] floats
        hipMemsetAsync(out, 0, sizeof(float) * N_NODES * D_FEAT, stream);
        hipMemsetAsync(deg, 0, sizeof(float) * N_NODES, stream);
        sage_edge_atomic_kernel<<<(N_EDGES * D_FEAT + 255) / 256, 256, 0, stream>>>(
            rel, pattern, src, dst, out, deg);
        sage_node_atomic_kernel<<<(N_NODES * D_FEAT + 255) / 256, 256, 0, stream>>>(
            rel, deg, out);
    }
}

// Round 4
// 432.413 us; speedup vs baseline: 1.3127x; 1.0755x over previous
//
#include <hip/hip_runtime.h>

#define N_NODES 100000
#define N_EDGES 1600000
#define D_FEAT  32
#define CAP     64   // per-node capacity; deg ~ multinomial mean 16, max ~45

// ============ scatter: one thread per edge ============
// CS = cnt stride in ints (16 => one counter per 64B line, kills TCC
// same-line RMW serialization observed in round 3: 140us @ 0.3% VALU).

template<int CS>
__global__ void scatter_pair_kernel(const int* __restrict__ dst,
                                    const int* __restrict__ src,
                                    int*  __restrict__ cnt,     // [N*CS], pre-zeroed
                                    int2* __restrict__ list) {  // [N*CAP] (e, src)
    int e = blockIdx.x * blockDim.x + threadIdx.x;
    if (e >= N_EDGES) return;
    int d = dst[e];
    int s = src[e];
    int slot = atomicAdd(&cnt[d * CS], 1);
    if (slot < CAP) list[d * CAP + slot] = make_int2(e, s);
}

template<int CS>
__global__ void scatter_id_kernel(const int* __restrict__ dst,
                                  int* __restrict__ cnt,
                                  int* __restrict__ list) {
    int e = blockIdx.x * blockDim.x + threadIdx.x;
    if (e >= N_EDGES) return;
    int d = dst[e];
    int slot = atomicAdd(&cnt[d * CS], 1);
    if (slot < CAP) list[d * CAP + slot] = e;
}

// ============ gather: 8 lanes per node, float4 per lane ============
// Tier A: list holds (e, src) pairs -> no dependent src gather level.

template<int CS>
__global__ void gather_pair_kernel(const float4* __restrict__ rel4,  // [N*8]
                                   const float4* __restrict__ pat4,  // [E*8]
                                   const int*    __restrict__ cnt,
                                   const int2*   __restrict__ list,
                                   float4* __restrict__ out4) {
    int t = blockIdx.x * blockDim.x + threadIdx.x;  // t = n*8 + q
    int n = t >> 3;
    int q = t & 7;
    if (n >= N_NODES) return;

    int deg = cnt[n * CS];
    int m = min(deg, CAP);
    const int2* lp  = list + n * CAP;
    const int4* lp4 = (const int4*)lp;   // bucket stride 512B, 16B-aligned

    float4 sum = make_float4(0.f, 0.f, 0.f, 0.f);
    int j = 0;
    for (; j + 8 <= m; j += 8) {
        int4 a = lp4[(j >> 1) + 0];  // (e0,s0,e1,s1)
        int4 b = lp4[(j >> 1) + 1];
        int4 c = lp4[(j >> 1) + 2];
        int4 d = lp4[(j >> 1) + 3];
        float4 r0 = rel4[a.y * 8 + q], p0 = pat4[a.x * 8 + q];
        float4 r1 = rel4[a.w * 8 + q], p1 = pat4[a.z * 8 + q];
        float4 r2 = rel4[b.y * 8 + q], p2 = pat4[b.x * 8 + q];
        float4 r3 = rel4[b.w * 8 + q], p3 = pat4[b.z * 8 + q];
        float4 r4 = rel4[c.y * 8 + q], p4 = pat4[c.x * 8 + q];
        float4 r5 = rel4[c.w * 8 + q], p5 = pat4[c.z * 8 + q];
        float4 r6 = rel4[d.y * 8 + q], p6 = pat4[d.x * 8 + q];
        float4 r7 = rel4[d.w * 8 + q], p7 = pat4[d.z * 8 + q];
        sum.x += r0.x*p0.x; sum.y += r0.y*p0.y; sum.z += r0.z*p0.z; sum.w += r0.w*p0.w;
        sum.x += r1.x*p1.x; sum.y += r1.y*p1.y; sum.z += r1.z*p1.z; sum.w += r1.w*p1.w;
        sum.x += r2.x*p2.x; sum.y += r2.y*p2.y; sum.z += r2.z*p2.z; sum.w += r2.w*p2.w;
        sum.x += r3.x*p3.x; sum.y += r3.y*p3.y; sum.z += r3.z*p3.z; sum.w += r3.w*p3.w;
        sum.x += r4.x*p4.x; sum.y += r4.y*p4.y; sum.z += r4.z*p4.z; sum.w += r4.w*p4.w;
        sum.x += r5.x*p5.x; sum.y += r5.y*p5.y; sum.z += r5.z*p5.z; sum.w += r5.w*p5.w;
        sum.x += r6.x*p6.x; sum.y += r6.y*p6.y; sum.z += r6.z*p6.z; sum.w += r6.w*p6.w;
        sum.x += r7.x*p7.x; sum.y += r7.y*p7.y; sum.z += r7.z*p7.z; sum.w += r7.w*p7.w;
    }
    for (; j < m; ++j) {  // tail <= 7, loads independent across iterations
        int2 pr = lp[j];
        float4 r = rel4[pr.y * 8 + q], p = pat4[pr.x * 8 + q];
        sum.x += r.x*p.x; sum.y += r.y*p.y; sum.z += r.z*p.z; sum.w += r.w*p.w;
    }

    float inv = 1.0f / fmaxf((float)deg, 1.0f);
    float4 rl = rel4[n * 8 + q];
    float4 o;
    o.x = sum.x * inv + rl.x;
    o.y = sum.y * inv + rl.y;
    o.z = sum.z * inv + rl.z;
    o.w = sum.w * inv + rl.w;
    out4[t] = o;
}

// Tier B/C: list holds edge ids; src gathered in-loop (round-3 style, float4 lanes).
template<int CS>
__global__ void gather_id_kernel(const float4* __restrict__ rel4,
                                 const float4* __restrict__ pat4,
                                 const int*    __restrict__ src,
                                 const int*    __restrict__ cnt,
                                 const int*    __restrict__ list,
                                 float4* __restrict__ out4) {
    int t = blockIdx.x * blockDim.x + threadIdx.x;
    int n = t >> 3;
    int q = t & 7;
    if (n >= N_NODES) return;

    int deg = cnt[n * CS];
    int m = min(deg, CAP);
    const int* lp = list + n * CAP;

    float4 sum = make_float4(0.f, 0.f, 0.f, 0.f);
    int j = 0;
    for (; j + 8 <= m; j += 8) {
        int4 a = *(const int4*)(lp + j);
        int4 b = *(const int4*)(lp + j + 4);
        int s0 = src[a.x], s1 = src[a.y], s2 = src[a.z], s3 = src[a.w];
        int s4 = src[b.x], s5 = src[b.y], s6 = src[b.z], s7 = src[b.w];
        float4 r0 = rel4[s0 * 8 + q], p0 = pat4[a.x * 8 + q];
        float4 r1 = rel4[s1 * 8 + q], p1 = pat4[a.y * 8 + q];
        float4 r2 = rel4[s2 * 8 + q], p2 = pat4[a.z * 8 + q];
        float4 r3 = rel4[s3 * 8 + q], p3 = pat4[a.w * 8 + q];
        float4 r4 = rel4[s4 * 8 + q], p4 = pat4[b.x * 8 + q];
        float4 r5 = rel4[s5 * 8 + q], p5 = pat4[b.y * 8 + q];
        float4 r6 = rel4[s6 * 8 + q], p6 = pat4[b.z * 8 + q];
        float4 r7 = rel4[s7 * 8 + q], p7 = pat4[b.w * 8 + q];
        sum.x += r0.x*p0.x; sum.y += r0.y*p0.y; sum.z += r0.z*p0.z; sum.w += r0.w*p0.w;
        sum.x += r1.x*p1.x; sum.y += r1.y*p1.y; sum.z += r1.z*p1.z; sum.w += r1.w*p1.w;
        sum.x += r2.x*p2.x; sum.y += r2.y*p2.y; sum.z += r2.z*p2.z; sum.w += r2.w*p2.w;
        sum.x += r3.x*p3.x; sum.y += r3.y*p3.y; sum.z += r3.z*p3.z; sum.w += r3.w*p3.w;
        sum.x += r4.x*p4.x; sum.y += r4.y*p4.y; sum.z += r4.z*p4.z; sum.w += r4.w*p4.w;
        sum.x += r5.x*p5.x; sum.y += r5.y*p5.y; sum.z += r5.z*p5.z; sum.w += r5.w*p5.w;
        sum.x += r6.x*p6.x; sum.y += r6.y*p6.y; sum.z += r6.z*p6.z; sum.w += r6.w*p6.w;
        sum.x += r7.x*p7.x; sum.y += r7.y*p7.y; sum.z += r7.z*p7.z; sum.w += r7.w*p7.w;
    }
    for (; j < m; ++j) {
        int e = lp[j];
        int s = src[e];
        float4 r = rel4[s * 8 + q], p = pat4[e * 8 + q];
        sum.x += r.x*p.x; sum.y += r.y*p.y; sum.z += r.z*p.z; sum.w += r.w*p.w;
    }

    float inv = 1.0f / fmaxf((float)deg, 1.0f);
    float4 rl = rel4[n * 8 + q];
    float4 o;
    o.x = sum.x * inv + rl.x;
    o.y = sum.y * inv + rl.y;
    o.z = sum.z * inv + rl.z;
    o.w = sum.w * inv + rl.w;
    out4[t] = o;
}

// ============ fallback (atomic path) ============
__global__ void sage_edge_atomic_kernel(const float* __restrict__ rel,
                                        const float* __restrict__ pattern,
                                        const int*   __restrict__ src,
                                        const int*   __restrict__ dst,
                                        float* __restrict__ sums,
                                        float* __restrict__ deg) {
    int i = blockIdx.x * blockDim.x + threadIdx.x;
    if (i >= N_EDGES * D_FEAT) return;
    int e = i >> 5;
    int f = i & 31;
    float m = rel[src[e] * D_FEAT + f] * pattern[i];
    atomicAdd(&sums[dst[e] * D_FEAT + f], m);
    if (f == 0) atomicAdd(&deg[dst[e]], 1.0f);
}

__global__ void sage_node_atomic_kernel(const float* __restrict__ rel,
                                        const float* __restrict__ deg,
                                        float* __restrict__ out) {
    int i = blockIdx.x * blockDim.x + threadIdx.x;
    if (i >= N_NODES * D_FEAT) return;
    out[i] = out[i] / fmaxf(deg[i >> 5], 1.0f) + rel[i];
}

extern "C" void kernel_launch(void* const* d_in, const int* in_sizes, int n_in,
                              void* d_out, int out_size, void* d_ws, size_t ws_size,
                              hipStream_t stream) {
    const float* rel     = (const float*)d_in[0];
    const float* pattern = (const float*)d_in[1];
    const int*   src     = (const int*)d_in[2];
    const int*   dst     = (const int*)d_in[3];
    float* out = (float*)d_out;

    const float4* rel4 = (const float4*)rel;
    const float4* pat4 = (const float4*)pattern;
    float4* out4 = (float4*)out;

    const size_t needA = (size_t)N_NODES * 16 * 4 + (size_t)N_NODES * CAP * 8;  // 57.6 MB
    const size_t needB = (size_t)N_NODES * 16 * 4 + (size_t)N_NODES * CAP * 4;  // 32.0 MB
    const size_t needC = (size_t)N_NODES * (CAP + 1) * 4;                       // 26.0 MB

    const int scatter_grid = (N_EDGES + 255) / 256;
    const int gather_grid  = (N_NODES * 8 + 255) / 256;

    if (ws_size >= needA) {
        // Tier A: line-padded counters + (e,src) pair list
        int*  cnt  = (int*)d_ws;                        // [N*16], one counter / 64B line
        int2* list = (int2*)(cnt + (size_t)N_NODES*16); // [N*CAP]
        hipMemsetAsync(cnt, 0, (size_t)N_NODES * 16 * 4, stream);
        scatter_pair_kernel<16><<<scatter_grid, 256, 0, stream>>>(dst, src, cnt, list);
        gather_pair_kernel<16><<<gather_grid, 256, 0, stream>>>(rel4, pat4, cnt, list, out4);
    } else if (ws_size >= needB) {
        // Tier B: line-padded counters + id list
        int* cnt  = (int*)d_ws;
        int* list = cnt + (size_t)N_NODES * 16;
        hipMemsetAsync(cnt, 0, (size_t)N_NODES * 16 * 4, stream);
        scatter_id_kernel<16><<<scatter_grid, 256, 0, stream>>>(dst, cnt, list);
        gather_id_kernel<16><<<gather_grid, 256, 0, stream>>>(rel4, pat4, src, cnt, list, out4);
    } else if (ws_size >= needC) {
        // Tier C: round-3 layout (known to fit)
        int* cnt  = (int*)d_ws;
        int* list = cnt + N_NODES;
        hipMemsetAsync(cnt, 0, (size_t)N_NODES * 4, stream);
        scatter_id_kernel<1><<<scatter_grid, 256, 0, stream>>>(dst, cnt, list);
        gather_id_kernel<1><<<gather_grid, 256, 0, stream>>>(rel4, pat4, src, cnt, list, out4);
    } else {
        // atomic fallback
        float* deg = (float*)d_ws;
        hipMemsetAsync(out, 0, sizeof(float) * N_NODES * D_FEAT, stream);
        hipMemsetAsync(deg, 0, sizeof(float) * N_NODES, stream);
        sage_edge_atomic_kernel<<<(N_EDGES * D_FEAT + 255) / 256, 256, 0, stream>>>(
            rel, pattern, src, dst, out, deg);
        sage_node_atomic_kernel<<<(N_NODES * D_FEAT + 255) / 256, 256, 0, stream>>>(
            rel, deg, out);
    }
}